// Round 1
// baseline (291.666 us; speedup 1.0000x reference)
//
#include <hip/hip_runtime.h>
#include <hip/hip_bf16.h>

// BlockNonLocal: B=2, C=64, spatial N=8*32*32=8192.
// z = W @ softmax(x^T x) x^T + bias + x   (per batch), fp32 I/O, bf16 MFMA compute.

constexpr int NC = 64;         // channels
constexpr int NN = 8192;       // spatial size
constexpr int KVB = 64;        // KV tile
constexpr int NKV = NN / KVB;  // 128 tiles

typedef __attribute__((ext_vector_type(8))) short bf16x8;
typedef __attribute__((ext_vector_type(4))) float f32x4;

static __device__ __forceinline__ short f2bf(float f) {
    union { float f; unsigned u; } v; v.f = f;
    unsigned r = v.u + 0x7FFFu + ((v.u >> 16) & 1u);
    return (short)(r >> 16);
}

__global__ __launch_bounds__(256) void attn_nl_kernel(
    const float* __restrict__ x, const float* __restrict__ wmat,
    const float* __restrict__ wbias, float* __restrict__ out)
{
    // LDS: tile in both orientations + per-wave P buffer. All XOR-swizzled by row (^((row&7)<<3) in elems).
    __shared__ short Xcj[64 * 64];       // [c][j]  (PV A-frags, j contiguous)
    __shared__ short Xjc[64 * 64];       // [j][c]  (QK^T B-frags, c contiguous)
    __shared__ short Plds[4][16 * 64];   // per-wave [i][j]

    const int tid  = threadIdx.x;
    const int lane = tid & 63;
    const int wv   = tid >> 6;      // wave 0..3
    const int lo   = lane & 15;
    const int hi   = lane >> 4;     // 0..3

    const int qtile = blockIdx.x;   // 0..127
    const int batch = blockIdx.y;   // 0..1
    const int b_off = batch * NC * NN;
    const int qwave = qtile * 64 + wv * 16;   // this wave's 16 q rows
    const int qrow  = qwave + lo;

    // ---- Q A-fragments: slot (lane,e) = Q[qrow][c], c = kk*32 + hi*8 + e ----
    bf16x8 qf[2];
    #pragma unroll
    for (int kk = 0; kk < 2; ++kk)
        #pragma unroll
        for (int e = 0; e < 8; ++e) {
            int c = kk * 32 + hi * 8 + e;
            qf[kk][e] = f2bf(x[b_off + c * NN + qrow]);
        }

    f32x4 acc[4];                 // y^T accumulator: acc[ct][r] = y^T[ct*16+hi*4+r][lo]
    #pragma unroll
    for (int ct = 0; ct < 4; ++ct)
        #pragma unroll
        for (int r = 0; r < 4; ++r) acc[ct][r] = 0.0f;
    float mrow[4], lrow[4];       // online softmax state for rows i = hi*4 + r
    #pragma unroll
    for (int r = 0; r < 4; ++r) { mrow[r] = -INFINITY; lrow[r] = 0.0f; }

    // staging assignment: thread -> (c row, j quarter)
    const int sc = tid >> 2;      // 0..63
    const int sq = tid & 3;       // 0..3
    const float* xrow = x + b_off + sc * NN + sq * 16;

    for (int jb = 0; jb < NKV; ++jb) {
        const int jbase = jb * KVB;
        __syncthreads();   // protect previous iteration's LDS reads

        // ---- stage 64x64 fp32 tile -> bf16 LDS in both orientations ----
        float fl[16];
        *(float4*)&fl[0]  = *(const float4*)(xrow + jbase + 0);
        *(float4*)&fl[4]  = *(const float4*)(xrow + jbase + 4);
        *(float4*)&fl[8]  = *(const float4*)(xrow + jbase + 8);
        *(float4*)&fl[12] = *(const float4*)(xrow + jbase + 12);
        short h[16];
        #pragma unroll
        for (int e = 0; e < 16; ++e) h[e] = f2bf(fl[e]);

        {   // Xcj: row sc, cols sq*16..+15 (two b128 stores)
            bf16x8 v0, v1;
            #pragma unroll
            for (int e = 0; e < 8; ++e) { v0[e] = h[e]; v1[e] = h[8 + e]; }
            int base = sc * 64 + sq * 16;
            int sw = (sc & 7) << 3;
            *(bf16x8*)&Xcj[(base) ^ sw]     = v0;
            *(bf16x8*)&Xcj[(base + 8) ^ sw] = v1;
        }
        #pragma unroll
        for (int jj = 0; jj < 16; ++jj) {   // Xjc: transposed scatter
            int j = sq * 16 + jj;
            Xjc[(j * 64 + sc) ^ ((j & 7) << 3)] = h[jj];
        }
        __syncthreads();

        // ---- QK^T: S[i=hi*4+r][j=jt*16+lo] ----
        f32x4 s[4];
        #pragma unroll
        for (int jt = 0; jt < 4; ++jt) {
            #pragma unroll
            for (int r = 0; r < 4; ++r) s[jt][r] = 0.0f;
            int j = jt * 16 + lo;
            #pragma unroll
            for (int kk = 0; kk < 2; ++kk) {
                bf16x8 kf = *(const bf16x8*)&Xjc[(j * 64 + kk * 32 + hi * 8) ^ ((j & 7) << 3)];
                s[jt] = __builtin_amdgcn_mfma_f32_16x16x32_bf16(qf[kk], kf, s[jt], 0, 0, 0);
            }
        }

        // ---- online softmax (rows i = hi*4+r; reduce over lo lanes + jt regs) ----
        float tm[4];
        #pragma unroll
        for (int r = 0; r < 4; ++r)
            tm[r] = fmaxf(fmaxf(s[0][r], s[1][r]), fmaxf(s[2][r], s[3][r]));
        #pragma unroll
        for (int d = 1; d < 16; d <<= 1)
            #pragma unroll
            for (int r = 0; r < 4; ++r)
                tm[r] = fmaxf(tm[r], __shfl_xor(tm[r], d));

        float scl4[4];
        #pragma unroll
        for (int r = 0; r < 4; ++r) {
            float mnew = fmaxf(mrow[r], tm[r]);
            scl4[r] = __expf(mrow[r] - mnew);
            mrow[r] = mnew;
        }

        float rs[4] = {0.f, 0.f, 0.f, 0.f};
        #pragma unroll
        for (int jt = 0; jt < 4; ++jt)
            #pragma unroll
            for (int r = 0; r < 4; ++r) {
                float p = __expf(s[jt][r] - mrow[r]);
                rs[r] += p;
                int i = hi * 4 + r;
                Plds[wv][(i * 64 + jt * 16 + lo) ^ ((i & 7) << 3)] = f2bf(p);
            }
        #pragma unroll
        for (int d = 1; d < 16; d <<= 1)
            #pragma unroll
            for (int r = 0; r < 4; ++r)
                rs[r] += __shfl_xor(rs[r], d);
        #pragma unroll
        for (int r = 0; r < 4; ++r)
            lrow[r] = lrow[r] * scl4[r] + rs[r];

        // broadcast rescale factor to the y^T lanes (lane's i = lo)
        {
            int srcl = (lo >> 2) << 4;
            float b0 = __shfl(scl4[0], srcl), b1 = __shfl(scl4[1], srcl);
            float b2 = __shfl(scl4[2], srcl), b3 = __shfl(scl4[3], srcl);
            int rr = lo & 3;
            float scl = rr == 0 ? b0 : rr == 1 ? b1 : rr == 2 ? b2 : b3;
            #pragma unroll
            for (int ct = 0; ct < 4; ++ct)
                #pragma unroll
                for (int r = 0; r < 4; ++r) acc[ct][r] *= scl;
        }

        asm volatile("s_waitcnt lgkmcnt(0)" ::: "memory");  // P writes visible to own-wave reads

        // ---- PV: y^T[c][i] += sum_j V^T[c][j] P^T[j][i]  (j-map = kk*32+hi*8+e both sides) ----
        bf16x8 pf[2];
        #pragma unroll
        for (int kk = 0; kk < 2; ++kk)
            pf[kk] = *(const bf16x8*)&Plds[wv][(lo * 64 + kk * 32 + hi * 8) ^ ((lo & 7) << 3)];
        #pragma unroll
        for (int ct = 0; ct < 4; ++ct) {
            int c = ct * 16 + lo;
            #pragma unroll
            for (int kk = 0; kk < 2; ++kk) {
                bf16x8 vf = *(const bf16x8*)&Xcj[(c * 64 + kk * 32 + hi * 8) ^ ((c & 7) << 3)];
                acc[ct] = __builtin_amdgcn_mfma_f32_16x16x32_bf16(vf, pf[kk], acc[ct], 0, 0, 0);
            }
        }
    }

    // ---- normalize: need 1/l for i = lo ----
    float linv;
    {
        int srcl = (lo >> 2) << 4;
        float b0 = __shfl(lrow[0], srcl), b1 = __shfl(lrow[1], srcl);
        float b2 = __shfl(lrow[2], srcl), b3 = __shfl(lrow[3], srcl);
        int rr = lo & 3;
        float li = rr == 0 ? b0 : rr == 1 ? b1 : rr == 2 ? b2 : b3;
        linv = 1.0f / li;
    }

    // ---- fused 1x1 conv via MFMA: z^T[o][i] = sum_c W[o][c] y^T[c][i] ----
    // shared c-map: c = kk*32 + (e>>2)*16 + hi*4 + (e&3)
    bf16x8 yf[2];
    #pragma unroll
    for (int kk = 0; kk < 2; ++kk)
        #pragma unroll
        for (int e = 0; e < 8; ++e)
            yf[kk][e] = f2bf(acc[kk * 2 + (e >> 2)][e & 3] * linv);

    f32x4 z[4];
    #pragma unroll
    for (int ot = 0; ot < 4; ++ot) {
        #pragma unroll
        for (int r = 0; r < 4; ++r) z[ot][r] = 0.0f;
        int o = ot * 16 + lo;
        #pragma unroll
        for (int kk = 0; kk < 2; ++kk) {
            float4 wa = *(const float4*)&wmat[o * 64 + kk * 32 + hi * 4];
            float4 wb = *(const float4*)&wmat[o * 64 + kk * 32 + 16 + hi * 4];
            bf16x8 wf;
            wf[0] = f2bf(wa.x); wf[1] = f2bf(wa.y); wf[2] = f2bf(wa.z); wf[3] = f2bf(wa.w);
            wf[4] = f2bf(wb.x); wf[5] = f2bf(wb.y); wf[6] = f2bf(wb.z); wf[7] = f2bf(wb.w);
            z[ot] = __builtin_amdgcn_mfma_f32_16x16x32_bf16(wf, yf[kk], z[ot], 0, 0, 0);
        }
    }

    // ---- bias + residual + store (z^T layout: col i=lo, row o=ot*16+hi*4+r) ----
    #pragma unroll
    for (int ot = 0; ot < 4; ++ot)
        #pragma unroll
        for (int r = 0; r < 4; ++r) {
            int o = ot * 16 + hi * 4 + r;
            int idx = b_off + o * NN + qwave + lo;
            out[idx] = z[ot][r] + wbias[o] + x[idx];
        }
}

extern "C" void kernel_launch(void* const* d_in, const int* in_sizes, int n_in,
                              void* d_out, int out_size, void* d_ws, size_t ws_size,
                              hipStream_t stream) {
    const float* x  = (const float*)d_in[0];
    const float* w  = (const float*)d_in[1];
    const float* b  = (const float*)d_in[2];
    float* out = (float*)d_out;
    dim3 grid(NN / 64, 2);
    attn_nl_kernel<<<grid, 256, 0, stream>>>(x, w, b, out);
}

// Round 2
// 213.100 us; speedup vs baseline: 1.3687x; 1.3687x over previous
//
#include <hip/hip_runtime.h>
#include <hip/hip_bf16.h>

// BlockNonLocal: B=2, C=64, spatial N=8*32*32=8192.
// z = W @ softmax(x^T x) x^T + bias + x   (per batch), fp32 I/O, bf16 MFMA compute.
// Round 2: flash-decoding split-K (4 splits) for occupancy (1 -> 4 waves/SIMD),
// combine kernel fuses merge + 1x1 conv + bias + residual.

constexpr int NC = 64;         // channels
constexpr int NN = 8192;       // spatial size
constexpr int KVB = 64;        // KV tile
constexpr int NKV = NN / KVB;  // 128 tiles
constexpr int NSPLIT = 4;
constexpr int TPS = NKV / NSPLIT;  // 32 tiles per split

typedef __attribute__((ext_vector_type(8))) short bf16x8;
typedef __attribute__((ext_vector_type(4))) float f32x4;

static __device__ __forceinline__ short f2bf(float f) {
    union { float f; unsigned u; } v; v.f = f;
    unsigned r = v.u + 0x7FFFu + ((v.u >> 16) & 1u);
    return (short)(r >> 16);
}

// ---------------------------------------------------------------------------
// Shared main loop body (flash attention over tiles [jb0, jb1) ).
// On return: acc = unnormalized y^T fragments, mrow/lrow = softmax state.
// ---------------------------------------------------------------------------
struct AttnState {
    f32x4 acc[4];
    float mrow[4], lrow[4];
};

static __device__ __forceinline__ void attn_loop(
    const float* __restrict__ x, int b_off, int qwave, int jb0, int jb1,
    short* Xcj, short* Xjc, short* Pw, AttnState& st,
    int tid, int lane, int lo, int hi)
{
    // ---- Q A-fragments: slot (lane,e) = Q[qrow][c], c = kk*32 + hi*8 + e ----
    const int qrow = qwave + lo;
    bf16x8 qf[2];
    #pragma unroll
    for (int kk = 0; kk < 2; ++kk)
        #pragma unroll
        for (int e = 0; e < 8; ++e) {
            int c = kk * 32 + hi * 8 + e;
            qf[kk][e] = f2bf(x[b_off + c * NN + qrow]);
        }

    #pragma unroll
    for (int ct = 0; ct < 4; ++ct)
        #pragma unroll
        for (int r = 0; r < 4; ++r) st.acc[ct][r] = 0.0f;
    #pragma unroll
    for (int r = 0; r < 4; ++r) { st.mrow[r] = -INFINITY; st.lrow[r] = 0.0f; }

    const int sc = tid >> 2;      // staging: c row 0..63
    const int sq = tid & 3;       // j quarter
    const float* xrow = x + b_off + sc * NN + sq * 16;

    for (int jb = jb0; jb < jb1; ++jb) {
        const int jbase = jb * KVB;
        __syncthreads();

        float fl[16];
        *(float4*)&fl[0]  = *(const float4*)(xrow + jbase + 0);
        *(float4*)&fl[4]  = *(const float4*)(xrow + jbase + 4);
        *(float4*)&fl[8]  = *(const float4*)(xrow + jbase + 8);
        *(float4*)&fl[12] = *(const float4*)(xrow + jbase + 12);
        short h[16];
        #pragma unroll
        for (int e = 0; e < 16; ++e) h[e] = f2bf(fl[e]);

        {
            bf16x8 v0, v1;
            #pragma unroll
            for (int e = 0; e < 8; ++e) { v0[e] = h[e]; v1[e] = h[8 + e]; }
            int base = sc * 64 + sq * 16;
            int sw = (sc & 7) << 3;
            *(bf16x8*)&Xcj[(base) ^ sw]     = v0;
            *(bf16x8*)&Xcj[(base + 8) ^ sw] = v1;
        }
        #pragma unroll
        for (int jj = 0; jj < 16; ++jj) {
            int j = sq * 16 + jj;
            Xjc[(j * 64 + sc) ^ ((j & 7) << 3)] = h[jj];
        }
        __syncthreads();

        // ---- QK^T ----
        f32x4 s[4];
        #pragma unroll
        for (int jt = 0; jt < 4; ++jt) {
            #pragma unroll
            for (int r = 0; r < 4; ++r) s[jt][r] = 0.0f;
            int j = jt * 16 + lo;
            #pragma unroll
            for (int kk = 0; kk < 2; ++kk) {
                bf16x8 kf = *(const bf16x8*)&Xjc[(j * 64 + kk * 32 + hi * 8) ^ ((j & 7) << 3)];
                s[jt] = __builtin_amdgcn_mfma_f32_16x16x32_bf16(qf[kk], kf, s[jt], 0, 0, 0);
            }
        }

        // ---- online softmax ----
        float tm[4];
        #pragma unroll
        for (int r = 0; r < 4; ++r)
            tm[r] = fmaxf(fmaxf(s[0][r], s[1][r]), fmaxf(s[2][r], s[3][r]));
        #pragma unroll
        for (int d = 1; d < 16; d <<= 1)
            #pragma unroll
            for (int r = 0; r < 4; ++r)
                tm[r] = fmaxf(tm[r], __shfl_xor(tm[r], d));

        float scl4[4];
        #pragma unroll
        for (int r = 0; r < 4; ++r) {
            float mnew = fmaxf(st.mrow[r], tm[r]);
            scl4[r] = __expf(st.mrow[r] - mnew);
            st.mrow[r] = mnew;
        }

        float rs[4] = {0.f, 0.f, 0.f, 0.f};
        #pragma unroll
        for (int jt = 0; jt < 4; ++jt)
            #pragma unroll
            for (int r = 0; r < 4; ++r) {
                float p = __expf(s[jt][r] - st.mrow[r]);
                rs[r] += p;
                int i = hi * 4 + r;
                Pw[(i * 64 + jt * 16 + lo) ^ ((i & 7) << 3)] = f2bf(p);
            }
        #pragma unroll
        for (int d = 1; d < 16; d <<= 1)
            #pragma unroll
            for (int r = 0; r < 4; ++r)
                rs[r] += __shfl_xor(rs[r], d);
        #pragma unroll
        for (int r = 0; r < 4; ++r)
            st.lrow[r] = st.lrow[r] * scl4[r] + rs[r];

        {
            int srcl = (lo >> 2) << 4;
            float b0 = __shfl(scl4[0], srcl), b1 = __shfl(scl4[1], srcl);
            float b2 = __shfl(scl4[2], srcl), b3 = __shfl(scl4[3], srcl);
            int rr = lo & 3;
            float scl = rr == 0 ? b0 : rr == 1 ? b1 : rr == 2 ? b2 : b3;
            #pragma unroll
            for (int ct = 0; ct < 4; ++ct)
                #pragma unroll
                for (int r = 0; r < 4; ++r) st.acc[ct][r] *= scl;
        }

        asm volatile("s_waitcnt lgkmcnt(0)" ::: "memory");

        // ---- PV ----
        bf16x8 pf[2];
        #pragma unroll
        for (int kk = 0; kk < 2; ++kk)
            pf[kk] = *(const bf16x8*)&Pw[(lo * 64 + kk * 32 + hi * 8) ^ ((lo & 7) << 3)];
        #pragma unroll
        for (int ct = 0; ct < 4; ++ct) {
            int c = ct * 16 + lo;
            #pragma unroll
            for (int kk = 0; kk < 2; ++kk) {
                bf16x8 vf = *(const bf16x8*)&Xcj[(c * 64 + kk * 32 + hi * 8) ^ ((c & 7) << 3)];
                st.acc[ct] = __builtin_amdgcn_mfma_f32_16x16x32_bf16(vf, pf[kk], st.acc[ct], 0, 0, 0);
            }
        }
    }
}

// ---------------------------------------------------------------------------
// Split-K partial kernel: grid (128, 2, NSPLIT)
// ---------------------------------------------------------------------------
__global__ __launch_bounds__(256) void attn_partial_kernel(
    const float* __restrict__ x, float* __restrict__ ypart, float* __restrict__ ml)
{
    __shared__ short Xcj[64 * 64];
    __shared__ short Xjc[64 * 64];
    __shared__ short Plds[4][16 * 64];

    const int tid  = threadIdx.x;
    const int lane = tid & 63;
    const int wv   = tid >> 6;
    const int lo   = lane & 15;
    const int hi   = lane >> 4;

    const int batch = blockIdx.y;
    const int split = blockIdx.z;
    const int b_off = batch * NC * NN;
    const int qwave = blockIdx.x * 64 + wv * 16;

    AttnState st;
    attn_loop(x, b_off, qwave, split * TPS, (split + 1) * TPS,
              Xcj, Xjc, Plds[wv], st, tid, lane, lo, hi);

    // write unnormalized y^T partial: [split][batch][c][NN]
    float* yp = ypart + (size_t)((split * 2 + batch) * 64) * NN;
    #pragma unroll
    for (int ct = 0; ct < 4; ++ct)
        #pragma unroll
        for (int r = 0; r < 4; ++r) {
            int c = ct * 16 + hi * 4 + r;
            yp[c * NN + qwave + lo] = st.acc[ct][r];
        }
    if (lo == 0) {
        float* mlp = ml + (size_t)((split * 2 + batch) * NN) * 2;
        #pragma unroll
        for (int r = 0; r < 4; ++r) {
            int i = qwave + hi * 4 + r;
            mlp[i * 2 + 0] = st.mrow[r];
            mlp[i * 2 + 1] = st.lrow[r];
        }
    }
}

// ---------------------------------------------------------------------------
// Combine: merge splits, normalize, 1x1 conv + bias + residual. grid (128, 2)
// ---------------------------------------------------------------------------
__global__ __launch_bounds__(256) void combine_conv_kernel(
    const float* __restrict__ x, const float* __restrict__ wmat,
    const float* __restrict__ wbias, const float* __restrict__ ypart,
    const float* __restrict__ ml, float* __restrict__ out)
{
    const int tid  = threadIdx.x;
    const int lane = tid & 63;
    const int wv   = tid >> 6;
    const int lo   = lane & 15;
    const int hi   = lane >> 4;

    const int batch = blockIdx.y;
    const int b_off = batch * NC * NN;
    const int qwave = blockIdx.x * 64 + wv * 16;
    const int i     = qwave + lo;     // this lane's column (q index)

    // merge weights for row i
    float ms[NSPLIT], ls[NSPLIT];
    #pragma unroll
    for (int s = 0; s < NSPLIT; ++s) {
        const float* mlp = ml + ((size_t)((s * 2 + batch) * NN) + i) * 2;
        ms[s] = mlp[0]; ls[s] = mlp[1];
    }
    float M = ms[0];
    #pragma unroll
    for (int s = 1; s < NSPLIT; ++s) M = fmaxf(M, ms[s]);
    float wsc[NSPLIT]; float L = 0.0f;
    #pragma unroll
    for (int s = 0; s < NSPLIT; ++s) { wsc[s] = __expf(ms[s] - M); L += wsc[s] * ls[s]; }
    const float linv = 1.0f / L;

    float accm[4][4];
    #pragma unroll
    for (int ct = 0; ct < 4; ++ct)
        #pragma unroll
        for (int r = 0; r < 4; ++r) accm[ct][r] = 0.0f;
    for (int s = 0; s < NSPLIT; ++s) {
        const float* yp = ypart + (size_t)((s * 2 + batch) * 64) * NN;
        #pragma unroll
        for (int ct = 0; ct < 4; ++ct)
            #pragma unroll
            for (int r = 0; r < 4; ++r) {
                int c = ct * 16 + hi * 4 + r;
                accm[ct][r] += wsc[s] * yp[c * NN + qwave + lo];
            }
    }

    // ---- fused 1x1 conv via MFMA (c-map: c = kk*32 + (e>>2)*16 + hi*4 + (e&3)) ----
    bf16x8 yf[2];
    #pragma unroll
    for (int kk = 0; kk < 2; ++kk)
        #pragma unroll
        for (int e = 0; e < 8; ++e)
            yf[kk][e] = f2bf(accm[kk * 2 + (e >> 2)][e & 3] * linv);

    f32x4 z[4];
    #pragma unroll
    for (int ot = 0; ot < 4; ++ot) {
        #pragma unroll
        for (int r = 0; r < 4; ++r) z[ot][r] = 0.0f;
        int o = ot * 16 + lo;
        #pragma unroll
        for (int kk = 0; kk < 2; ++kk) {
            float4 wa = *(const float4*)&wmat[o * 64 + kk * 32 + hi * 4];
            float4 wb = *(const float4*)&wmat[o * 64 + kk * 32 + 16 + hi * 4];
            bf16x8 wf;
            wf[0] = f2bf(wa.x); wf[1] = f2bf(wa.y); wf[2] = f2bf(wa.z); wf[3] = f2bf(wa.w);
            wf[4] = f2bf(wb.x); wf[5] = f2bf(wb.y); wf[6] = f2bf(wb.z); wf[7] = f2bf(wb.w);
            z[ot] = __builtin_amdgcn_mfma_f32_16x16x32_bf16(wf, yf[kk], z[ot], 0, 0, 0);
        }
    }

    #pragma unroll
    for (int ot = 0; ot < 4; ++ot)
        #pragma unroll
        for (int r = 0; r < 4; ++r) {
            int o = ot * 16 + hi * 4 + r;
            int idx = b_off + o * NN + qwave + lo;
            out[idx] = z[ot][r] + wbias[o] + x[idx];
        }
}

// ---------------------------------------------------------------------------
// Fallback: original single-kernel path (used only if ws is too small)
// ---------------------------------------------------------------------------
__global__ __launch_bounds__(256) void attn_nl_kernel(
    const float* __restrict__ x, const float* __restrict__ wmat,
    const float* __restrict__ wbias, float* __restrict__ out)
{
    __shared__ short Xcj[64 * 64];
    __shared__ short Xjc[64 * 64];
    __shared__ short Plds[4][16 * 64];

    const int tid  = threadIdx.x;
    const int lane = tid & 63;
    const int wv   = tid >> 6;
    const int lo   = lane & 15;
    const int hi   = lane >> 4;

    const int batch = blockIdx.y;
    const int b_off = batch * NC * NN;
    const int qwave = blockIdx.x * 64 + wv * 16;

    AttnState st;
    attn_loop(x, b_off, qwave, 0, NKV, Xcj, Xjc, Plds[wv], st, tid, lane, lo, hi);

    float linv;
    {
        int srcl = (lo >> 2) << 4;
        float b0 = __shfl(st.lrow[0], srcl), b1 = __shfl(st.lrow[1], srcl);
        float b2 = __shfl(st.lrow[2], srcl), b3 = __shfl(st.lrow[3], srcl);
        int rr = lo & 3;
        float li = rr == 0 ? b0 : rr == 1 ? b1 : rr == 2 ? b2 : b3;
        linv = 1.0f / li;
    }

    bf16x8 yf[2];
    #pragma unroll
    for (int kk = 0; kk < 2; ++kk)
        #pragma unroll
        for (int e = 0; e < 8; ++e)
            yf[kk][e] = f2bf(st.acc[kk * 2 + (e >> 2)][e & 3] * linv);

    f32x4 z[4];
    #pragma unroll
    for (int ot = 0; ot < 4; ++ot) {
        #pragma unroll
        for (int r = 0; r < 4; ++r) z[ot][r] = 0.0f;
        int o = ot * 16 + lo;
        #pragma unroll
        for (int kk = 0; kk < 2; ++kk) {
            float4 wa = *(const float4*)&wmat[o * 64 + kk * 32 + hi * 4];
            float4 wb = *(const float4*)&wmat[o * 64 + kk * 32 + 16 + hi * 4];
            bf16x8 wf;
            wf[0] = f2bf(wa.x); wf[1] = f2bf(wa.y); wf[2] = f2bf(wa.z); wf[3] = f2bf(wa.w);
            wf[4] = f2bf(wb.x); wf[5] = f2bf(wb.y); wf[6] = f2bf(wb.z); wf[7] = f2bf(wb.w);
            z[ot] = __builtin_amdgcn_mfma_f32_16x16x32_bf16(wf, yf[kk], z[ot], 0, 0, 0);
        }
    }

    #pragma unroll
    for (int ot = 0; ot < 4; ++ot)
        #pragma unroll
        for (int r = 0; r < 4; ++r) {
            int o = ot * 16 + hi * 4 + r;
            int idx = b_off + o * NN + qwave + lo;
            out[idx] = z[ot][r] + wbias[o] + x[idx];
        }
}

extern "C" void kernel_launch(void* const* d_in, const int* in_sizes, int n_in,
                              void* d_out, int out_size, void* d_ws, size_t ws_size,
                              hipStream_t stream) {
    const float* x  = (const float*)d_in[0];
    const float* w  = (const float*)d_in[1];
    const float* b  = (const float*)d_in[2];
    float* out = (float*)d_out;

    const size_t ypart_elems = (size_t)NSPLIT * 2 * 64 * NN;       // 4,194,304
    const size_t ml_elems    = (size_t)NSPLIT * 2 * NN * 2;        //   131,072
    const size_t need = (ypart_elems + ml_elems) * sizeof(float);  // ~17.3 MB

    if (ws_size >= need) {
        float* ypart = (float*)d_ws;
        float* ml    = ypart + ypart_elems;
        attn_partial_kernel<<<dim3(NN / 64, 2, NSPLIT), 256, 0, stream>>>(x, ypart, ml);
        combine_conv_kernel<<<dim3(NN / 64, 2), 256, 0, stream>>>(x, w, b, ypart, ml, out);
    } else {
        attn_nl_kernel<<<dim3(NN / 64, 2), 256, 0, stream>>>(x, w, b, out);
    }
}

// Round 5
// 190.531 us; speedup vs baseline: 1.5308x; 1.1185x over previous
//
#include <hip/hip_runtime.h>
#include <hip/hip_bf16.h>

// BlockNonLocal: B=2, C=64, N=8192.
// z = W @ softmax(x^T x) x^T + bias + x  per batch.  fp32 I/O, bf16 MFMA.
// Round 3 design, resubmit #2 (rounds 3 and 4 were both infra failures —
// broker timeout, then container failure; no measurements taken):
// prep kernel converts x -> bf16 in [j][c] and [c][j] layouts once;
// attention kernel reads fragments straight from global (L1/L2-resident),
// no barriers, fixed per-row max surrogate m_i = ||q_i||^2 (no online max),
// row-sum l via ones-MFMA. Split-K (runtime nsplit) + combine w/ fused conv.

constexpr int NC = 64;
constexpr int NN = 8192;
constexpr int NKV = 128;       // 64-wide KV tiles

typedef __attribute__((ext_vector_type(8))) short bf16x8;
typedef __attribute__((ext_vector_type(4))) float f32x4;

static __device__ __forceinline__ short f2bf(float f) {
    union { float f; unsigned u; } v; v.f = f;
    unsigned r = v.u + 0x7FFFu + ((v.u >> 16) & 1u);
    return (short)(r >> 16);
}
static __device__ __forceinline__ float bf2f(short h) {
    union { unsigned u; float f; } v;
    v.u = ((unsigned)(unsigned short)h) << 16;
    return v.f;
}

// ---------------------------------------------------------------------------
// Prep: x fp32 [b][c][j] -> Xcj bf16 (same layout) and Xjc bf16 ([b][j][c]).
// grid (128, 2), 256 threads; one 64x64 tile per block.
// ---------------------------------------------------------------------------
__global__ __launch_bounds__(256) void prep_kernel(
    const float* __restrict__ x, short* __restrict__ Xjc, short* __restrict__ Xcj)
{
    __shared__ short T[64 * 64];   // [j][c], xor-swizzled
    const int tid = threadIdx.x;
    const int jt = blockIdx.x;     // j-tile 0..127
    const int b  = blockIdx.y;
    const int bo = b * NC * NN;
    const int sc = tid >> 2, sq = tid & 3;

    const float* xr = x + bo + sc * NN + jt * 64 + sq * 16;
    float fl[16];
    *(float4*)&fl[0]  = *(const float4*)(xr + 0);
    *(float4*)&fl[4]  = *(const float4*)(xr + 4);
    *(float4*)&fl[8]  = *(const float4*)(xr + 8);
    *(float4*)&fl[12] = *(const float4*)(xr + 12);
    short h[16];
    #pragma unroll
    for (int e = 0; e < 16; ++e) h[e] = f2bf(fl[e]);

    bf16x8 v0, v1;
    #pragma unroll
    for (int e = 0; e < 8; ++e) { v0[e] = h[e]; v1[e] = h[8 + e]; }
    *(bf16x8*)&Xcj[bo + sc * NN + jt * 64 + sq * 16]     = v0;
    *(bf16x8*)&Xcj[bo + sc * NN + jt * 64 + sq * 16 + 8] = v1;

    #pragma unroll
    for (int jj = 0; jj < 16; ++jj) {
        int j = sq * 16 + jj;
        T[(j * 64 + sc) ^ ((j & 7) << 3)] = h[jj];
    }
    __syncthreads();

    const int jr = tid >> 2, cq = tid & 3;
    bf16x8 a0 = *(const bf16x8*)&T[(jr * 64 + cq * 16) ^ ((jr & 7) << 3)];
    bf16x8 a1 = *(const bf16x8*)&T[(jr * 64 + cq * 16 + 8) ^ ((jr & 7) << 3)];
    *(bf16x8*)&Xjc[bo + (jt * 64 + jr) * 64 + cq * 16]     = a0;
    *(bf16x8*)&Xjc[bo + (jt * 64 + jr) * 64 + cq * 16 + 8] = a1;
}

// ---------------------------------------------------------------------------
// Flash-decoding attention partials. grid (64, 2, nsplit), 256 threads.
// Each wave owns 32 q rows. No barriers; K/V fragments read from global.
// ---------------------------------------------------------------------------
__global__ __launch_bounds__(256) void attn_fd_kernel(
    const short* __restrict__ Xjc, const short* __restrict__ Xcj,
    float* __restrict__ ypart, float* __restrict__ lpart, int tps)
{
    __shared__ short Pl[4][32 * 64];   // per-wave P, xor-swizzled

    const int tid  = threadIdx.x;
    const int lane = tid & 63;
    const int wv   = tid >> 6;
    const int lo   = lane & 15;
    const int hi   = lane >> 4;

    const int b  = blockIdx.y;
    const int sp = blockIdx.z;
    const int bo = b * NC * NN;
    const int qbase = blockIdx.x * 128 + wv * 32;
    short* Pw = Pl[wv];

    // Q fragments: (lane,e) -> Q[qbase+qs*16+lo][c], c = kk*32 + hi*8 + e
    bf16x8 qf[2][2];
    #pragma unroll
    for (int qs = 0; qs < 2; ++qs)
        #pragma unroll
        for (int kk = 0; kk < 2; ++kk)
            qf[qs][kk] = *(const bf16x8*)&Xjc[bo + (qbase + qs * 16 + lo) * 64 + kk * 32 + hi * 8];

    // fixed per-row shift m_i = ||q_i||^2 (bf16-rounded q; any nearby shift works)
    float mrow[2][4];
    #pragma unroll
    for (int qs = 0; qs < 2; ++qs) {
        float v = 0.0f;
        #pragma unroll
        for (int kk = 0; kk < 2; ++kk)
            #pragma unroll
            for (int e = 0; e < 8; ++e) { float q = bf2f(qf[qs][kk][e]); v += q * q; }
        v += __shfl_xor(v, 16);
        v += __shfl_xor(v, 32);        // lanes sharing lo now hold full ||q||^2
        #pragma unroll
        for (int r = 0; r < 4; ++r) mrow[qs][r] = __shfl(v, hi * 4 + r);
    }

    f32x4 acc[2][4];    // y^T fragments
    f32x4 lacc[2];      // row-sum accumulator (ones-MFMA)
    #pragma unroll
    for (int qs = 0; qs < 2; ++qs) {
        #pragma unroll
        for (int ct = 0; ct < 4; ++ct)
            #pragma unroll
            for (int r = 0; r < 4; ++r) acc[qs][ct][r] = 0.0f;
        #pragma unroll
        for (int r = 0; r < 4; ++r) lacc[qs][r] = 0.0f;
    }
    bf16x8 ones;
    #pragma unroll
    for (int e = 0; e < 8; ++e) ones[e] = (short)0x3F80;   // bf16 1.0

    const int jb0 = sp * tps, jb1 = jb0 + tps;
    bf16x8 kfc[4][2], kfn[4][2];
    #pragma unroll
    for (int jt = 0; jt < 4; ++jt)
        #pragma unroll
        for (int kk = 0; kk < 2; ++kk)
            kfc[jt][kk] = *(const bf16x8*)&Xjc[bo + (jb0 * 64 + jt * 16 + lo) * 64 + kk * 32 + hi * 8];

    for (int jb = jb0; jb < jb1; ++jb) {
        // V fragments for this tile (consumed after softmax -> latency hidden)
        bf16x8 vf[4][2];
        #pragma unroll
        for (int ct = 0; ct < 4; ++ct)
            #pragma unroll
            for (int kk = 0; kk < 2; ++kk)
                vf[ct][kk] = *(const bf16x8*)&Xcj[bo + (ct * 16 + lo) * NN + jb * 64 + kk * 32 + hi * 8];
        // prefetch next tile's K fragments
        const bool more = (jb + 1 < jb1);
        if (more) {
            #pragma unroll
            for (int jt = 0; jt < 4; ++jt)
                #pragma unroll
                for (int kk = 0; kk < 2; ++kk)
                    kfn[jt][kk] = *(const bf16x8*)&Xjc[bo + ((jb + 1) * 64 + jt * 16 + lo) * 64 + kk * 32 + hi * 8];
        }

        // QK^T: s[qs][jt][r] = S[i = qs*16+hi*4+r][j = jb*64 + jt*16+lo]
        f32x4 s[2][4];
        #pragma unroll
        for (int qs = 0; qs < 2; ++qs)
            #pragma unroll
            for (int jt = 0; jt < 4; ++jt) {
                #pragma unroll
                for (int r = 0; r < 4; ++r) s[qs][jt][r] = 0.0f;
                #pragma unroll
                for (int kk = 0; kk < 2; ++kk)
                    s[qs][jt] = __builtin_amdgcn_mfma_f32_16x16x32_bf16(qf[qs][kk], kfc[jt][kk], s[qs][jt], 0, 0, 0);
            }

        // P = exp(S - m), straight to LDS (no reductions, no rescale)
        #pragma unroll
        for (int qs = 0; qs < 2; ++qs)
            #pragma unroll
            for (int jt = 0; jt < 4; ++jt)
                #pragma unroll
                for (int r = 0; r < 4; ++r) {
                    float p = __expf(s[qs][jt][r] - mrow[qs][r]);
                    int i = qs * 16 + hi * 4 + r;
                    Pw[(i * 64 + jt * 16 + lo) ^ ((i & 7) << 3)] = f2bf(p);
                }
        asm volatile("s_waitcnt lgkmcnt(0)" ::: "memory");
        __builtin_amdgcn_sched_barrier(0);

        // P^T B-fragments
        bf16x8 pf[2][2];
        #pragma unroll
        for (int qs = 0; qs < 2; ++qs)
            #pragma unroll
            for (int kk = 0; kk < 2; ++kk) {
                int row = qs * 16 + lo;
                pf[qs][kk] = *(const bf16x8*)&Pw[(row * 64 + kk * 32 + hi * 8) ^ ((row & 7) << 3)];
            }

        // l += ones * P^T   (row-sum via MFMA)
        #pragma unroll
        for (int qs = 0; qs < 2; ++qs)
            #pragma unroll
            for (int kk = 0; kk < 2; ++kk)
                lacc[qs] = __builtin_amdgcn_mfma_f32_16x16x32_bf16(ones, pf[qs][kk], lacc[qs], 0, 0, 0);

        // y^T += V^T * P^T
        #pragma unroll
        for (int qs = 0; qs < 2; ++qs)
            #pragma unroll
            for (int ct = 0; ct < 4; ++ct)
                #pragma unroll
                for (int kk = 0; kk < 2; ++kk)
                    acc[qs][ct] = __builtin_amdgcn_mfma_f32_16x16x32_bf16(vf[ct][kk], pf[qs][kk], acc[qs][ct], 0, 0, 0);

        if (more) {
            #pragma unroll
            for (int jt = 0; jt < 4; ++jt)
                #pragma unroll
                for (int kk = 0; kk < 2; ++kk)
                    kfc[jt][kk] = kfn[jt][kk];
        }
    }

    // write partials: y^T [sp][b][c][N] and l [sp][b][N]
    float* yp = ypart + (size_t)(sp * 2 + b) * NC * NN;
    #pragma unroll
    for (int qs = 0; qs < 2; ++qs)
        #pragma unroll
        for (int ct = 0; ct < 4; ++ct)
            #pragma unroll
            for (int r = 0; r < 4; ++r) {
                int c = ct * 16 + hi * 4 + r;
                yp[c * NN + qbase + qs * 16 + lo] = acc[qs][ct][r];
            }
    if (hi == 0) {
        #pragma unroll
        for (int qs = 0; qs < 2; ++qs)
            lpart[(sp * 2 + b) * NN + qbase + qs * 16 + lo] = lacc[qs][0];
    }
}

// ---------------------------------------------------------------------------
// Combine: sum splits (shared shift => additive), normalize, 1x1 conv + bias
// + residual. grid (128, 2), 256 threads.
// ---------------------------------------------------------------------------
__global__ __launch_bounds__(256) void combine_kernel(
    const float* __restrict__ x, const float* __restrict__ wmat,
    const float* __restrict__ wbias, const float* __restrict__ ypart,
    const float* __restrict__ lpart, float* __restrict__ out, int nsplit)
{
    const int tid  = threadIdx.x;
    const int lane = tid & 63;
    const int wv   = tid >> 6;
    const int lo   = lane & 15;
    const int hi   = lane >> 4;

    const int batch = blockIdx.y;
    const int b_off = batch * NC * NN;
    const int qwave = blockIdx.x * 64 + wv * 16;
    const int i     = qwave + lo;

    float L = 0.0f;
    for (int s = 0; s < nsplit; ++s) L += lpart[(s * 2 + batch) * NN + i];
    const float linv = 1.0f / L;

    float accm[4][4];
    #pragma unroll
    for (int ct = 0; ct < 4; ++ct)
        #pragma unroll
        for (int r = 0; r < 4; ++r) accm[ct][r] = 0.0f;
    for (int s = 0; s < nsplit; ++s) {
        const float* yp = ypart + (size_t)(s * 2 + batch) * NC * NN;
        #pragma unroll
        for (int ct = 0; ct < 4; ++ct)
            #pragma unroll
            for (int r = 0; r < 4; ++r) {
                int c = ct * 16 + hi * 4 + r;
                accm[ct][r] += yp[c * NN + qwave + lo];
            }
    }

    // fused 1x1 conv via MFMA (c-map: c = kk*32 + (e>>2)*16 + hi*4 + (e&3))
    bf16x8 yf[2];
    #pragma unroll
    for (int kk = 0; kk < 2; ++kk)
        #pragma unroll
        for (int e = 0; e < 8; ++e)
            yf[kk][e] = f2bf(accm[kk * 2 + (e >> 2)][e & 3] * linv);

    f32x4 z[4];
    #pragma unroll
    for (int ot = 0; ot < 4; ++ot) {
        #pragma unroll
        for (int r = 0; r < 4; ++r) z[ot][r] = 0.0f;
        int o = ot * 16 + lo;
        #pragma unroll
        for (int kk = 0; kk < 2; ++kk) {
            float4 wa = *(const float4*)&wmat[o * 64 + kk * 32 + hi * 4];
            float4 wb = *(const float4*)&wmat[o * 64 + kk * 32 + 16 + hi * 4];
            bf16x8 wf;
            wf[0] = f2bf(wa.x); wf[1] = f2bf(wa.y); wf[2] = f2bf(wa.z); wf[3] = f2bf(wa.w);
            wf[4] = f2bf(wb.x); wf[5] = f2bf(wb.y); wf[6] = f2bf(wb.z); wf[7] = f2bf(wb.w);
            z[ot] = __builtin_amdgcn_mfma_f32_16x16x32_bf16(wf, yf[kk], z[ot], 0, 0, 0);
        }
    }

    #pragma unroll
    for (int ot = 0; ot < 4; ++ot)
        #pragma unroll
        for (int r = 0; r < 4; ++r) {
            int o = ot * 16 + hi * 4 + r;
            int idx = b_off + o * NN + qwave + lo;
            out[idx] = z[ot][r] + wbias[o] + x[idx];
        }
}

// ---------------------------------------------------------------------------
// Ultimate fallback (no workspace): round-1 single-kernel path.
// ---------------------------------------------------------------------------
__global__ __launch_bounds__(256) void attn_nl_kernel(
    const float* __restrict__ x, const float* __restrict__ wmat,
    const float* __restrict__ wbias, float* __restrict__ out)
{
    __shared__ short Xcj[64 * 64];
    __shared__ short Xjc[64 * 64];
    __shared__ short Plds[4][16 * 64];

    const int tid  = threadIdx.x;
    const int lane = tid & 63;
    const int wv   = tid >> 6;
    const int lo   = lane & 15;
    const int hi   = lane >> 4;

    const int batch = blockIdx.y;
    const int b_off = batch * NC * NN;
    const int qwave = blockIdx.x * 64 + wv * 16;
    const int qrow  = qwave + lo;

    bf16x8 qf[2];
    #pragma unroll
    for (int kk = 0; kk < 2; ++kk)
        #pragma unroll
        for (int e = 0; e < 8; ++e) {
            int c = kk * 32 + hi * 8 + e;
            qf[kk][e] = f2bf(x[b_off + c * NN + qrow]);
        }

    f32x4 acc[4];
    #pragma unroll
    for (int ct = 0; ct < 4; ++ct)
        #pragma unroll
        for (int r = 0; r < 4; ++r) acc[ct][r] = 0.0f;
    float mrow[4], lrow[4];
    #pragma unroll
    for (int r = 0; r < 4; ++r) { mrow[r] = -INFINITY; lrow[r] = 0.0f; }

    const int sc = tid >> 2;
    const int sq = tid & 3;
    const float* xrow = x + b_off + sc * NN + sq * 16;

    for (int jb = 0; jb < NKV; ++jb) {
        const int jbase = jb * 64;
        __syncthreads();

        float fl[16];
        *(float4*)&fl[0]  = *(const float4*)(xrow + jbase + 0);
        *(float4*)&fl[4]  = *(const float4*)(xrow + jbase + 4);
        *(float4*)&fl[8]  = *(const float4*)(xrow + jbase + 8);
        *(float4*)&fl[12] = *(const float4*)(xrow + jbase + 12);
        short h[16];
        #pragma unroll
        for (int e = 0; e < 16; ++e) h[e] = f2bf(fl[e]);

        {
            bf16x8 v0, v1;
            #pragma unroll
            for (int e = 0; e < 8; ++e) { v0[e] = h[e]; v1[e] = h[8 + e]; }
            int base = sc * 64 + sq * 16;
            int sw = (sc & 7) << 3;
            *(bf16x8*)&Xcj[(base) ^ sw]     = v0;
            *(bf16x8*)&Xcj[(base + 8) ^ sw] = v1;
        }
        #pragma unroll
        for (int jj = 0; jj < 16; ++jj) {
            int j = sq * 16 + jj;
            Xjc[(j * 64 + sc) ^ ((j & 7) << 3)] = h[jj];
        }
        __syncthreads();

        f32x4 s[4];
        #pragma unroll
        for (int jt = 0; jt < 4; ++jt) {
            #pragma unroll
            for (int r = 0; r < 4; ++r) s[jt][r] = 0.0f;
            int j = jt * 16 + lo;
            #pragma unroll
            for (int kk = 0; kk < 2; ++kk) {
                bf16x8 kf = *(const bf16x8*)&Xjc[(j * 64 + kk * 32 + hi * 8) ^ ((j & 7) << 3)];
                s[jt] = __builtin_amdgcn_mfma_f32_16x16x32_bf16(qf[kk], kf, s[jt], 0, 0, 0);
            }
        }

        float tm[4];
        #pragma unroll
        for (int r = 0; r < 4; ++r)
            tm[r] = fmaxf(fmaxf(s[0][r], s[1][r]), fmaxf(s[2][r], s[3][r]));
        #pragma unroll
        for (int d = 1; d < 16; d <<= 1)
            #pragma unroll
            for (int r = 0; r < 4; ++r)
                tm[r] = fmaxf(tm[r], __shfl_xor(tm[r], d));

        float scl4[4];
        #pragma unroll
        for (int r = 0; r < 4; ++r) {
            float mnew = fmaxf(mrow[r], tm[r]);
            scl4[r] = __expf(mrow[r] - mnew);
            mrow[r] = mnew;
        }

        float rs[4] = {0.f, 0.f, 0.f, 0.f};
        #pragma unroll
        for (int jt = 0; jt < 4; ++jt)
            #pragma unroll
            for (int r = 0; r < 4; ++r) {
                float p = __expf(s[jt][r] - mrow[r]);
                rs[r] += p;
                int i = hi * 4 + r;
                Plds[wv][(i * 64 + jt * 16 + lo) ^ ((i & 7) << 3)] = f2bf(p);
            }
        #pragma unroll
        for (int d = 1; d < 16; d <<= 1)
            #pragma unroll
            for (int r = 0; r < 4; ++r)
                rs[r] += __shfl_xor(rs[r], d);
        #pragma unroll
        for (int r = 0; r < 4; ++r)
            lrow[r] = lrow[r] * scl4[r] + rs[r];

        {
            int srcl = (lo >> 2) << 4;
            float b0 = __shfl(scl4[0], srcl), b1 = __shfl(scl4[1], srcl);
            float b2 = __shfl(scl4[2], srcl), b3 = __shfl(scl4[3], srcl);
            int rr = lo & 3;
            float scl = rr == 0 ? b0 : rr == 1 ? b1 : rr == 2 ? b2 : b3;
            #pragma unroll
            for (int ct = 0; ct < 4; ++ct)
                #pragma unroll
                for (int r = 0; r < 4; ++r) acc[ct][r] *= scl;
        }

        asm volatile("s_waitcnt lgkmcnt(0)" ::: "memory");

        bf16x8 pf[2];
        #pragma unroll
        for (int kk = 0; kk < 2; ++kk)
            pf[kk] = *(const bf16x8*)&Plds[wv][(lo * 64 + kk * 32 + hi * 8) ^ ((lo & 7) << 3)];
        #pragma unroll
        for (int ct = 0; ct < 4; ++ct) {
            int c = ct * 16 + lo;
            #pragma unroll
            for (int kk = 0; kk < 2; ++kk) {
                bf16x8 vf = *(const bf16x8*)&Xcj[(c * 64 + kk * 32 + hi * 8) ^ ((c & 7) << 3)];
                acc[ct] = __builtin_amdgcn_mfma_f32_16x16x32_bf16(vf, pf[kk], acc[ct], 0, 0, 0);
            }
        }
    }

    float linv;
    {
        int srcl = (lo >> 2) << 4;
        float c0 = __shfl(lrow[0], srcl), c1 = __shfl(lrow[1], srcl);
        float c2 = __shfl(lrow[2], srcl), c3 = __shfl(lrow[3], srcl);
        int rr = lo & 3;
        float li = rr == 0 ? c0 : rr == 1 ? c1 : rr == 2 ? c2 : c3;
        linv = 1.0f / li;
    }

    bf16x8 yf[2];
    #pragma unroll
    for (int kk = 0; kk < 2; ++kk)
        #pragma unroll
        for (int e = 0; e < 8; ++e)
            yf[kk][e] = f2bf(acc[kk * 2 + (e >> 2)][e & 3] * linv);

    f32x4 z[4];
    #pragma unroll
    for (int ot = 0; ot < 4; ++ot) {
        #pragma unroll
        for (int r = 0; r < 4; ++r) z[ot][r] = 0.0f;
        int o = ot * 16 + lo;
        #pragma unroll
        for (int kk = 0; kk < 2; ++kk) {
            float4 wa = *(const float4*)&wmat[o * 64 + kk * 32 + hi * 4];
            float4 wb = *(const float4*)&wmat[o * 64 + kk * 32 + 16 + hi * 4];
            bf16x8 wf;
            wf[0] = f2bf(wa.x); wf[1] = f2bf(wa.y); wf[2] = f2bf(wa.z); wf[3] = f2bf(wa.w);
            wf[4] = f2bf(wb.x); wf[5] = f2bf(wb.y); wf[6] = f2bf(wb.z); wf[7] = f2bf(wb.w);
            z[ot] = __builtin_amdgcn_mfma_f32_16x16x32_bf16(wf, yf[kk], z[ot], 0, 0, 0);
        }
    }

    #pragma unroll
    for (int ot = 0; ot < 4; ++ot)
        #pragma unroll
        for (int r = 0; r < 4; ++r) {
            int o = ot * 16 + hi * 4 + r;
            int idx = b_off + o * NN + qwave + lo;
            out[idx] = z[ot][r] + wbias[o] + x[idx];
        }
}

extern "C" void kernel_launch(void* const* d_in, const int* in_sizes, int n_in,
                              void* d_out, int out_size, void* d_ws, size_t ws_size,
                              hipStream_t stream) {
    const float* x  = (const float*)d_in[0];
    const float* w  = (const float*)d_in[1];
    const float* b  = (const float*)d_in[2];
    float* out = (float*)d_out;

    const size_t xhalf = (size_t)2 * NC * NN;   // shorts per orientation (both batches)
    auto need = [&](int ns) -> size_t {
        return xhalf * 2 * sizeof(short)
             + (size_t)ns * 2 * NC * NN * sizeof(float)
             + (size_t)ns * 2 * NN * sizeof(float);
    };

    int ns = 0;
    if      (ws_size >= need(4)) ns = 4;
    else if (ws_size >= need(2)) ns = 2;
    else if (ws_size >= need(1)) ns = 1;

    if (ns) {
        short* Xjc = (short*)d_ws;
        short* Xcj = Xjc + xhalf;
        float* ypart = (float*)(Xcj + xhalf);
        float* lpart = ypart + (size_t)ns * 2 * NC * NN;
        const int tps = NKV / ns;
        prep_kernel<<<dim3(NKV, 2), 256, 0, stream>>>(x, Xjc, Xcj);
        attn_fd_kernel<<<dim3(NN / 128, 2, ns), 256, 0, stream>>>(Xjc, Xcj, ypart, lpart, tps);
        combine_kernel<<<dim3(NN / 64, 2), 256, 0, stream>>>(x, w, b, ypart, lpart, out, ns);
    } else {
        attn_nl_kernel<<<dim3(NN / 64, 2), 256, 0, stream>>>(x, w, b, out);
    }
}